// Round 9
// baseline (14579.652 us; speedup 1.0000x reference)
//
#include <hip/hip_runtime.h>
#include <math.h>

#define HD 1024
#define CD 256
#define TT 512
#define GD 4096                 // 4*H
#define NWG 256
#define NTH 1024
#define WPB 16                  // waves per block
#define NWAVE (NWG*WPB)         // 4096
#define LAMF 0.05f

typedef unsigned long long ull;
typedef unsigned short ushortt;
typedef _Float16 hh2 __attribute__((ext_vector_type(2)));

// ---------------- fp16 weight copies (built per call) ---------------------
__device__ __align__(16) ushortt hM1[GD * CD];    //  2 MB : Wih1[:,:H]@Ww0
__device__ __align__(16) ushortt hM2[GD * HD];    //  8 MB : Wih2[:,:H]@Ww1
__device__ __align__(16) ushortt hM3[GD * HD];    //  8 MB : Wih3@Ww2
__device__ __align__(16) ushortt hW1b[GD * HD];   //  8 MB : Wih1[:,H:]
__device__ __align__(16) ushortt hWhh1[GD * HD];  //  8 MB
__device__ __align__(16) ushortt hW2b[GD * HD];   //  8 MB : Wih2[:,H:]
__device__ __align__(16) ushortt hWhh2[GD * HD];  //  8 MB
__device__ __align__(16) ushortt hWhh3[GD * HD];  //  8 MB
__device__ __align__(16) ushortt hVw1[CD * HD];   // .5 MB
__device__ __align__(16) ushortt hVw2[HD * HD];   //  2 MB
__device__ __align__(16) ushortt hVw3[HD * HD];   //  2 MB

// ---------------- cross-WG vectors (only matvec outputs are published) ----
__device__ __align__(16) float d_g1[GD], d_g2[GD], d_g3[GD];
__device__ __align__(16) float d_z1[CD];
__device__ __align__(16) float d_rec2[HD], d_rec3[HD];
__device__ int d_arr[NWG][32];
__device__ int d_rel;

__global__ void pc_init() { d_arr[threadIdx.x][0] = 0; if (threadIdx.x == 0) d_rel = 0; }

__device__ __forceinline__ float sigf(float x)     { return 1.f / (1.f + __expf(-x)); }
__device__ __forceinline__ float tanhfast(float x) { return 1.f - 2.f / (1.f + __expf(2.f * x)); }

__device__ __forceinline__ ushortt f2h(float x) {
  union { ushortt u; _Float16 h; } c; c.h = (_Float16)x; return c.u;
}
__device__ __forceinline__ float h2f(ushortt u) {
  union { ushortt u; _Float16 h; } c; c.u = u; return (float)c.h;
}
__device__ __forceinline__ unsigned packh2(float a, float b) {
  union { unsigned u; hh2 h; } c; c.h = hh2{(_Float16)a, (_Float16)b}; return c.u;
}
__device__ __forceinline__ float fd2(unsigned a, unsigned b, float c) {
  union { unsigned u; hh2 h; } ua, ub; ua.u = a; ub.u = b;
  return __builtin_amdgcn_fdot2(ua.h, ub.h, c, false);
}

__device__ __forceinline__ float cload(const float* p) {
  return __hip_atomic_load(p, __ATOMIC_RELAXED, __HIP_MEMORY_SCOPE_AGENT);
}
__device__ __forceinline__ void cstore(float* p, float v) {
  __hip_atomic_store(p, v, __ATOMIC_RELAXED, __HIP_MEMORY_SCOPE_AGENT);
}
__device__ __forceinline__ float2 cload2(const float* p) {
  union { ull u; float2 f; } c;
  c.u = __hip_atomic_load((const ull*)p, __ATOMIC_RELAXED, __HIP_MEMORY_SCOPE_AGENT);
  return c.f;
}

// Distributed epoch barrier (R3-proven; no cache-invalidating fences).
__device__ __forceinline__ void gbar(int& ep) {
  ++ep;
  __syncthreads();
  const int tid = threadIdx.x;
  if (blockIdx.x == 0) {
    if (tid >= 1 && tid < NWG) {
      while (__hip_atomic_load(&d_arr[tid][0], __ATOMIC_RELAXED, __HIP_MEMORY_SCOPE_AGENT) < ep)
        __builtin_amdgcn_s_sleep(1);
    }
    __syncthreads();
    if (tid == 0)
      __hip_atomic_store(&d_rel, ep, __ATOMIC_RELEASE, __HIP_MEMORY_SCOPE_AGENT);
  } else {
    if (tid == 0) {
      __hip_atomic_store(&d_arr[blockIdx.x][0], ep, __ATOMIC_RELEASE, __HIP_MEMORY_SCOPE_AGENT);
      while (__hip_atomic_load(&d_rel, __ATOMIC_RELAXED, __HIP_MEMORY_SCOPE_AGENT) < ep)
        __builtin_amdgcn_s_sleep(1);
    }
    __syncthreads();
  }
}

__device__ __forceinline__ float wredsum(float v) {
  #pragma unroll
  for (int off = 32; off; off >>= 1) v += __shfl_xor(v, off);
  return v;
}
__device__ __forceinline__ float wredmax(float v) {
  #pragma unroll
  for (int off = 32; off; off >>= 1) v = fmaxf(v, __shfl_xor(v, off));
  return v;
}

// fp32 dot (prologue only)
__device__ __forceinline__ float dotp(const float* __restrict__ w, const float* xv, int n, int lane) {
  float a0 = 0.f, a1 = 0.f, a2 = 0.f, a3 = 0.f;
  for (int c = lane * 4; c < n; c += 256) {
    const float4 wv = *(const float4*)(w + c);
    const float4 vv = *(const float4*)(xv + c);
    a0 = fmaf(wv.x, vv.x, a0); a1 = fmaf(wv.y, vv.y, a1);
    a2 = fmaf(wv.z, vv.z, a2); a3 = fmaf(wv.w, vv.w, a3);
  }
  return (a0 + a1) + (a2 + a3);
}

// fp16 dot over 1024 halves, weights loaded at use (secondary jobs)
__device__ __forceinline__ float dotH(const ushortt* __restrict__ w, const ushortt* xv, int lane) {
  const uint4 w0 = *(const uint4*)(w + lane * 8);
  const uint4 w1 = *(const uint4*)(w + lane * 8 + 512);
  const uint4 v0 = *(const uint4*)(xv + lane * 8);
  const uint4 v1 = *(const uint4*)(xv + lane * 8 + 512);
  float a = 0.f;
  a = fd2(w0.x, v0.x, a); a = fd2(w0.y, v0.y, a);
  a = fd2(w0.z, v0.z, a); a = fd2(w0.w, v0.w, a);
  a = fd2(w1.x, v1.x, a); a = fd2(w1.y, v1.y, a);
  a = fd2(w1.z, v1.z, a); a = fd2(w1.w, v1.w, a);
  return a;
}
// fp16 dot over 256 halves (at-use)
__device__ __forceinline__ float dotH256(const ushortt* __restrict__ w, const ushortt* xv, int lane) {
  const uint2 wv = *(const uint2*)(w + lane * 4);
  const uint2 vv = *(const uint2*)(xv + lane * 4);
  float a = fd2(wv.x, vv.x, 0.f);
  return fd2(wv.y, vv.y, a);
}

// prefetched-row variants: loads issued separately, consumed from registers
__device__ __forceinline__ void ldrow(const ushortt* __restrict__ w, int lane, uint4& w0, uint4& w1) {
  w0 = *(const uint4*)(w + lane * 8);
  w1 = *(const uint4*)(w + lane * 8 + 512);
}
__device__ __forceinline__ float dotR(const uint4 w0, const uint4 w1, const ushortt* xv, int lane) {
  const uint4 v0 = *(const uint4*)(xv + lane * 8);
  const uint4 v1 = *(const uint4*)(xv + lane * 8 + 512);
  float a = 0.f;
  a = fd2(w0.x, v0.x, a); a = fd2(w0.y, v0.y, a);
  a = fd2(w0.z, v0.z, a); a = fd2(w0.w, v0.w, a);
  a = fd2(w1.x, v1.x, a); a = fd2(w1.y, v1.y, a);
  a = fd2(w1.z, v1.z, a); a = fd2(w1.w, v1.w, a);
  return a;
}
__device__ __forceinline__ float dotR256(const uint2 w0, const ushortt* xv, int lane) {
  const uint2 vv = *(const uint2*)(xv + lane * 4);
  float a = fd2(w0.x, vv.x, 0.f);
  return fd2(w0.y, vv.y, a);
}

// pin: asm is a use+def of the regs -> load can't sink past it, value can't be
// re-materialized after it. Forces completion (vmcnt wait) at this point.
#define PIN4(u)  asm volatile("" : "+v"((u).x), "+v"((u).y), "+v"((u).z), "+v"((u).w))
#define PIN2(u)  asm volatile("" : "+v"((u).x), "+v"((u).y))

// ---------------- fp32->fp16 weight conversion ----------------------------
__global__ __launch_bounds__(256) void pc_conv(
    const float* __restrict__ Wih1, const float* __restrict__ Whh1,
    const float* __restrict__ Wih2, const float* __restrict__ Whh2,
    const float* __restrict__ Whh3, const float* __restrict__ Vw1,
    const float* __restrict__ Vw2,  const float* __restrict__ Vw3) {
  const size_t stride = (size_t)gridDim.x * 256;
  const size_t i0 = (size_t)blockIdx.x * 256 + threadIdx.x;
  for (size_t i = i0; i < (size_t)GD * HD; i += stride) {
    size_t r = i >> 10, c = i & 1023;
    size_t src = (r << 11) + HD + c;
    hW1b[i]  = f2h(Wih1[src]);
    hW2b[i]  = f2h(Wih2[src]);
    hWhh1[i] = f2h(Whh1[i]);
    hWhh2[i] = f2h(Whh2[i]);
    hWhh3[i] = f2h(Whh3[i]);
  }
  for (size_t i = i0; i < (size_t)HD * HD; i += stride) {
    hVw2[i] = f2h(Vw2[i]);
    hVw3[i] = f2h(Vw3[i]);
  }
  for (size_t i = i0; i < (size_t)CD * HD; i += stride) hVw1[i] = f2h(Vw1[i]);
}

// ---------------- fold GEMM: fp16 C[4096 x N] = A @ B ---------------------
__global__ __launch_bounds__(256) void pc_fold(
    const float* __restrict__ Wih1, const float* __restrict__ Wih2,
    const float* __restrict__ Wih3, const float* __restrict__ Ww0,
    const float* __restrict__ Ww1,  const float* __restrict__ Ww2) {
  int b = blockIdx.x;
  const float* A; const float* B; ushortt* C; int N, lda;
  if (b < 256)        { A = Wih1; B = Ww0; C = hM1; N = CD; lda = 2 * HD; }
  else if (b < 1280)  { A = Wih2; B = Ww1; C = hM2; N = HD; lda = 2 * HD; b -= 256; }
  else                { A = Wih3; B = Ww2; C = hM3; N = HD; lda = HD;     b -= 1280; }
  const int ctiles = N >> 6;
  const int rt = b / ctiles, ct = b - rt * ctiles;
  const int tid = threadIdx.x;
  const int tx = tid & 15, ty = tid >> 4;

  __shared__ float sA[16][65];
  __shared__ float sB[16][64];

  float acc[4][4] = {};
  const int ar = tid >> 2, aq = tid & 3;
  const int br = tid >> 4, bq = tid & 15;

  for (int kk = 0; kk < HD; kk += 16) {
    float4 av = *(const float4*)(A + (size_t)(rt * 64 + ar) * lda + kk + aq * 4);
    float4 bv = *(const float4*)(B + (size_t)(kk + br) * N + ct * 64 + bq * 4);
    __syncthreads();
    sA[aq * 4 + 0][ar] = av.x; sA[aq * 4 + 1][ar] = av.y;
    sA[aq * 4 + 2][ar] = av.z; sA[aq * 4 + 3][ar] = av.w;
    *(float4*)&sB[br][bq * 4] = bv;
    __syncthreads();
    #pragma unroll
    for (int k = 0; k < 16; ++k) {
      const float4 b4 = *(const float4*)&sB[k][tx * 4];
      const float a0 = sA[k][ty * 4 + 0], a1 = sA[k][ty * 4 + 1];
      const float a2 = sA[k][ty * 4 + 2], a3 = sA[k][ty * 4 + 3];
      acc[0][0] = fmaf(a0, b4.x, acc[0][0]); acc[0][1] = fmaf(a0, b4.y, acc[0][1]);
      acc[0][2] = fmaf(a0, b4.z, acc[0][2]); acc[0][3] = fmaf(a0, b4.w, acc[0][3]);
      acc[1][0] = fmaf(a1, b4.x, acc[1][0]); acc[1][1] = fmaf(a1, b4.y, acc[1][1]);
      acc[1][2] = fmaf(a1, b4.z, acc[1][2]); acc[1][3] = fmaf(a1, b4.w, acc[1][3]);
      acc[2][0] = fmaf(a2, b4.x, acc[2][0]); acc[2][1] = fmaf(a2, b4.y, acc[2][1]);
      acc[2][2] = fmaf(a2, b4.z, acc[2][2]); acc[2][3] = fmaf(a2, b4.w, acc[2][3]);
      acc[3][0] = fmaf(a3, b4.x, acc[3][0]); acc[3][1] = fmaf(a3, b4.y, acc[3][1]);
      acc[3][2] = fmaf(a3, b4.z, acc[3][2]); acc[3][3] = fmaf(a3, b4.w, acc[3][3]);
    }
  }
  #pragma unroll
  for (int i = 0; i < 4; ++i) {
    uint2 r = make_uint2(packh2(acc[i][0], acc[i][1]), packh2(acc[i][2], acc[i][3]));
    *(uint2*)(C + (size_t)(rt * 64 + ty * 4 + i) * N + ct * 64 + tx * 4) = r;
  }
}

__global__ __launch_bounds__(NTH, 1) void pc_main(
    const float* __restrict__ x,
    const float* __restrict__ Wih1, const float* __restrict__ Whh1,
    const float* __restrict__ bih1, const float* __restrict__ bhh1,
    const float* __restrict__ Vw1,  const float* __restrict__ Vb1,
    const float* __restrict__ Wih2, const float* __restrict__ Whh2,
    const float* __restrict__ bih2, const float* __restrict__ bhh2,
    const float* __restrict__ Vw2,  const float* __restrict__ Vb2,
    const float* __restrict__ Wih3, const float* __restrict__ Whh3,
    const float* __restrict__ bih3, const float* __restrict__ bhh3,
    const float* __restrict__ Vw3,  const float* __restrict__ Vb3,
    const float* __restrict__ Ww0,  const float* __restrict__ Wb0,
    const float* __restrict__ Ww1,  const float* __restrict__ Wb1,
    const float* __restrict__ Ww2,  const float* __restrict__ Wb2,
    const float* __restrict__ r1,   const float* __restrict__ r2,
    const float* __restrict__ r3,
    float* __restrict__ out) {
  const int tid  = threadIdx.x;
  const int lane = tid & 63;
  const int bid  = blockIdx.x;
  const int wid  = bid * WPB + (tid >> 6);
  const bool iswg0 = (bid == 0);
  const bool w0    = iswg0 && tid < 64;

  // per-WG local state: activations fp16 (matvec operands), cell states fp32
  __shared__ __align__(16) ushortt s_h1[HD], s_TD1[HD], s_h2[HD], s_TD2[HD], s_h3[HD];
  __shared__ __align__(16) float s_c1[HD], s_c2[HD], s_c3[HD];
  __shared__ __align__(16) ushortt s_small[CD];   // TD0 feeding next g1

  const int e = (tid < 512) ? (((tid + (bid << 3)) & 511) * 2) : 0;

  const int jR = ((wid & 3) == 1)  ? (wid >> 2) : -1;   // rec3 (P) / rec2 (Q)
  const int jZ = ((wid & 15) == 2) ? (wid >> 4) : -1;   // z1 (P)

  // per-wave fixed row pointers
  const ushortt* wpM2 = hM2   + (size_t)wid * HD;
  const ushortt* wpW2 = hW2b  + (size_t)wid * HD;
  const ushortt* wpH2 = hWhh2 + (size_t)wid * HD;
  const ushortt* wpM3 = hM3   + (size_t)wid * HD;
  const ushortt* wpH3 = hWhh3 + (size_t)wid * HD;
  const ushortt* wpM1 = hM1   + (size_t)wid * CD;
  const ushortt* wpW1 = hW1b  + (size_t)wid * HD;
  const ushortt* wpH1 = hWhh1 + (size_t)wid * HD;

  // prefetch registers (P-phase set and Q-phase set)
  uint4 pA0, pA1, pB0, pB1, pC0, pC1;             // hM2, hW2b, hWhh2
  uint4 qA0, qA1, qB0, qB1, qC0, qC1, qD0, qD1;   // hM3, hWhh3, hW1b, hWhh1
  uint2 qE;                                       // hM1

  int ep = 0;
  float loss_acc = 0.f, fll_acc = 0.f;
  float b1, b2, b3, vbR3 = 0.f, vbR2 = 0.f, vbZ = 0.f;

  // ---------------- prologue: fold biases, init state, g1(0) ---------------
  if (tid < 512) {
    int j = tid * 2;
    *(float2*)(s_c1 + j) = *(const float2*)(Wb0 + j);
    *(float2*)(s_c2 + j) = *(const float2*)(Wb1 + j);
    *(float2*)(s_c3 + j) = *(const float2*)(Wb2 + j);
  }
  __syncthreads();
  b1 = bih1[wid] + bhh1[wid] + wredsum(dotp(Wih1 + (size_t)wid * 2 * HD, s_c1, HD, lane));
  b2 = bih2[wid] + bhh2[wid] + wredsum(dotp(Wih2 + (size_t)wid * 2 * HD, s_c2, HD, lane));
  b3 = bih3[wid] + bhh3[wid] + wredsum(dotp(Wih3 + (size_t)wid * HD,     s_c3, HD, lane));
  if (jR >= 0) { vbR3 = Vb3[jR]; vbR2 = Vb2[jR]; }
  if (jZ >= 0) vbZ = Vb1[jZ];
  __syncthreads();
  if (tid < 512) {
    int j = tid * 2;
    const float2 z2 = make_float2(0.f, 0.f);
    *(float2*)(s_c1 + j) = z2; *(float2*)(s_c2 + j) = z2; *(float2*)(s_c3 + j) = z2;
    *(unsigned*)(s_h1 + j) = 0u; *(unsigned*)(s_TD1 + j) = 0u;
    *(unsigned*)(s_h2 + j) = 0u; *(unsigned*)(s_TD2 + j) = 0u;
    *(unsigned*)(s_h3 + j) = 0u;
  }
  if (tid < 64) {                       // softmax(r1) -> TD0(0); loss0(0)
    float4 z4 = *(const float4*)(r1 + tid * 4);
    float m = wredmax(fmaxf(fmaxf(z4.x, z4.y), fmaxf(z4.z, z4.w)));
    float e0 = __expf(z4.x - m), e1 = __expf(z4.y - m);
    float e2 = __expf(z4.z - m), e3 = __expf(z4.w - m);
    float inv = 1.f / wredsum((e0 + e1) + (e2 + e3));
    float p0 = e0 * inv, p1 = e1 * inv, p2 = e2 * inv, p3 = e3 * inv;
    float4 xv = *(const float4*)(x + tid * 4);
    *(uint2*)(s_small + tid * 4) =
        make_uint2(packh2(xv.x - p0, xv.y - p1), packh2(xv.z - p2, xv.w - p3));
    if (iswg0) {
      float u = xv.x * __logf(p0) + (1.f - xv.x) * __logf(1.f - p0)
              + xv.y * __logf(p1) + (1.f - xv.y) * __logf(1.f - p1)
              + xv.z * __logf(p2) + (1.f - xv.z) * __logf(1.f - p2)
              + xv.w * __logf(p3) + (1.f - xv.w) * __logf(1.f - p3);
      u = wredsum(u);
      if (tid == 0) { loss_acc -= u; fll_acc -= u; }
    }
  }
  __syncthreads();
  {                                     // g1(0) = M1@TD0(0) + b1
    float s = wredsum(dotH256(wpM1, s_small, lane));
    if (lane == 0) cstore(&d_g1[wid], s + b1);
  }
  // prefetch P(0) g2-row operands
  ldrow(wpM2, lane, pA0, pA1);
  ldrow(wpW2, lane, pB0, pB1);
  ldrow(wpH2, lane, pC0, pC1);
  PIN4(pA0); PIN4(pA1); PIN4(pB0); PIN4(pB1); PIN4(pC0); PIN4(pC1);
  gbar(ep);

  for (int t = 0; t < TT; ++t) {
    // ========== P(t): cell3(t-1), cell1(t) ; g2(t), z1(t), rec3(t-1) ======
    if (tid < 512) {
      if (t > 0) {                      // cell3(t-1)
        float2 gi = cload2(&d_g3[e]),          gf = cload2(&d_g3[e + HD]);
        float2 gg = cload2(&d_g3[e + 2 * HD]), go = cload2(&d_g3[e + 3 * HD]);
        float cA = sigf(gf.x) * s_c3[e]     + sigf(gi.x) * tanhfast(gg.x);
        float cB = sigf(gf.y) * s_c3[e + 1] + sigf(gi.y) * tanhfast(gg.y);
        float hA = sigf(go.x) * tanhfast(cA);
        float hB = sigf(go.y) * tanhfast(cB);
        s_c3[e] = cA; s_c3[e + 1] = cB;
        *(unsigned*)(s_h3 + e) = packh2(hA, hB);
      }
      {                                 // cell1(t)
        float2 gi = cload2(&d_g1[e]),          gf = cload2(&d_g1[e + HD]);
        float2 gg = cload2(&d_g1[e + 2 * HD]), go = cload2(&d_g1[e + 3 * HD]);
        float2 rc = (t == 0) ? *(const float2*)(r2 + e) : cload2(&d_rec2[e]);
        float cA = sigf(gf.x) * s_c1[e]     + sigf(gi.x) * tanhfast(gg.x);
        float cB = sigf(gf.y) * s_c1[e + 1] + sigf(gi.y) * tanhfast(gg.y);
        float hA = sigf(go.x) * tanhfast(cA);
        float hB = sigf(go.y) * tanhfast(cB);
        s_c1[e] = cA; s_c1[e + 1] = cB;
        *(unsigned*)(s_h1 + e)  = packh2(hA, hB);
        *(unsigned*)(s_TD1 + e) = packh2(hA - rc.x, hB - rc.y);
      }
    }
    // issue Q(t) prefetch (overlaps remaining P work + barrier)
    if (t < TT - 1) {
      ldrow(wpM3, lane, qA0, qA1);
      ldrow(wpH3, lane, qB0, qB1);
      ldrow(wpW1, lane, qC0, qC1);
      ldrow(wpH1, lane, qD0, qD1);
      qE = *(const uint2*)(wpM1 + lane * 4);
    }
    __syncthreads();
    if (w0) {                           // LAM * sum|TD1(t)|
      float a = 0.f;
      #pragma unroll
      for (int k = 0; k < 16; ++k) a += fabsf(h2f(s_TD1[tid + 64 * k]));
      a = wredsum(a);
      if (tid == 0) loss_acc += LAMF * a;
    }
    {                                   // g2(t) from prefetched regs
      float s = dotR(pA0, pA1, s_TD1, lane)
              + dotR(pB0, pB1, s_TD2, lane)
              + dotR(pC0, pC1, s_h2,  lane);
      s = wredsum(s);
      if (lane == 0) cstore(&d_g2[wid], s + b2);
    }
    if (t > 0 && jR >= 0) {             // rec3(t-1) = Vw3 @ h3(t-1)
      float s = wredsum(dotH(hVw3 + (size_t)jR * HD, s_h3, lane));
      if (lane == 0) cstore(&d_rec3[jR], s + vbR3);
    }
    if (jZ >= 0) {                      // z1(t) = Vw1 @ h1(t)
      float s = wredsum(dotH(hVw1 + (size_t)jZ * HD, s_h1, lane));
      if (lane == 0) cstore(&d_z1[jZ], s + vbZ);
    }
    if (t < TT - 1) {
      PIN4(qA0); PIN4(qA1); PIN4(qB0); PIN4(qB1);
      PIN4(qC0); PIN4(qC1); PIN4(qD0); PIN4(qD1); PIN2(qE);
    }
    gbar(ep);

    // ========== Q(t): cell2(t), softmax(z1) ; g3(t), g1(t+1), rec2(t) =====
    if (tid < 512) {                    // cell2(t)
      float2 gi = cload2(&d_g2[e]),          gf = cload2(&d_g2[e + HD]);
      float2 gg = cload2(&d_g2[e + 2 * HD]), go = cload2(&d_g2[e + 3 * HD]);
      float2 rc = (t == 0) ? *(const float2*)(r3 + e) : cload2(&d_rec3[e]);
      float cA = sigf(gf.x) * s_c2[e]     + sigf(gi.x) * tanhfast(gg.x);
      float cB = sigf(gf.y) * s_c2[e + 1] + sigf(gi.y) * tanhfast(gg.y);
      float hA = sigf(go.x) * tanhfast(cA);
      float hB = sigf(go.y) * tanhfast(cB);
      s_c2[e] = cA; s_c2[e + 1] = cB;
      *(unsigned*)(s_h2 + e)  = packh2(hA, hB);
      *(unsigned*)(s_TD2 + e) = packh2(hA - rc.x, hB - rc.y);
    }
    // issue P(t+1) prefetch
    if (t < TT - 1) {
      ldrow(wpM2, lane, pA0, pA1);
      ldrow(wpW2, lane, pB0, pB1);
      ldrow(wpH2, lane, pC0, pC1);
    }
    if (tid < 64) {                     // softmax(z1(t)) -> predictions[t], TD0(t+1)
      float2 za = cload2(&d_z1[tid * 4]), zb = cload2(&d_z1[tid * 4 + 2]);
      float m = wredmax(fmaxf(fmaxf(za.x, za.y), fmaxf(zb.x, zb.y)));
      float e0 = __expf(za.x - m), e1 = __expf(za.y - m);
      float e2 = __expf(zb.x - m), e3 = __expf(zb.y - m);
      float inv = 1.f / wredsum((e0 + e1) + (e2 + e3));
      float p0 = e0 * inv, p1 = e1 * inv, p2 = e2 * inv, p3 = e3 * inv;
      if (t < TT - 1) {
        float4 xv = *(const float4*)(x + (size_t)(t + 1) * CD + tid * 4);
        *(uint2*)(s_small + tid * 4) =
            make_uint2(packh2(xv.x - p0, xv.y - p1), packh2(xv.z - p2, xv.w - p3));
        if (iswg0) {                    // loss0(t+1)
          float u = xv.x * __logf(p0) + (1.f - xv.x) * __logf(1.f - p0)
                  + xv.y * __logf(p1) + (1.f - xv.y) * __logf(1.f - p1)
                  + xv.z * __logf(p2) + (1.f - xv.z) * __logf(1.f - p2)
                  + xv.w * __logf(p3) + (1.f - xv.w) * __logf(1.f - p3);
          u = wredsum(u);
          if (tid == 0) { loss_acc -= u; fll_acc -= u; }
        }
      }
      if (iswg0) {                      // predictions[t]
        float* po = out + 2 + (size_t)t * CD + tid * 4;
        po[0] = p0; po[1] = p1; po[2] = p2; po[3] = p3;
      }
    }
    __syncthreads();
    if (w0) {                           // LAM^2 * sum|TD2(t)|
      float a = 0.f;
      #pragma unroll
      for (int k = 0; k < 16; ++k) a += fabsf(h2f(s_TD2[tid + 64 * k]));
      a = wredsum(a);
      if (tid == 0) loss_acc += (LAMF * LAMF) * a;
    }
    if (t < TT - 1) {
      {                                 // g3(t) from prefetched regs
        float s = dotR(qA0, qA1, s_TD2, lane)
                + dotR(qB0, qB1, s_h3,  lane);
        s = wredsum(s);
        if (lane == 0) cstore(&d_g3[wid], s + b3);
      }
      {                                 // g1(t+1) from prefetched regs
        float s = dotR256(qE, s_small, lane)
                + dotR(qC0, qC1, s_TD1, lane)
                + dotR(qD0, qD1, s_h1,  lane);
        s = wredsum(s);
        if (lane == 0) cstore(&d_g1[wid], s + b1);
      }
      if (jR >= 0) {                    // rec2(t) = Vw2 @ h2(t)
        float s = wredsum(dotH(hVw2 + (size_t)jR * HD, s_h2, lane));
        if (lane == 0) cstore(&d_rec2[jR], s + vbR2);
      }
      PIN4(pA0); PIN4(pA1); PIN4(pB0); PIN4(pB1); PIN4(pC0); PIN4(pC1);
      gbar(ep);
    }
  }

  if (iswg0 && tid == 0) { out[0] = loss_acc; out[1] = fll_acc; }
}

extern "C" void kernel_launch(void* const* d_in, const int* in_sizes, int n_in,
                              void* d_out, int out_size, void* d_ws, size_t ws_size,
                              hipStream_t stream) {
  const float* x    = (const float*)d_in[0];
  const float* Wih1 = (const float*)d_in[1];
  const float* Whh1 = (const float*)d_in[2];
  const float* bih1 = (const float*)d_in[3];
  const float* bhh1 = (const float*)d_in[4];
  const float* Vw1  = (const float*)d_in[5];
  const float* Vb1  = (const float*)d_in[6];
  const float* Wih2 = (const float*)d_in[7];
  const float* Whh2 = (const float*)d_in[8];
  const float* bih2 = (const float*)d_in[9];
  const float* bhh2 = (const float*)d_in[10];
  const float* Vw2  = (const float*)d_in[11];
  const float* Vb2  = (const float*)d_in[12];
  const float* Wih3 = (const float*)d_in[13];
  const float* Whh3 = (const float*)d_in[14];
  const float* bih3 = (const float*)d_in[15];
  const float* bhh3 = (const float*)d_in[16];
  const float* Vw3  = (const float*)d_in[17];
  const float* Vb3  = (const float*)d_in[18];
  const float* Ww0  = (const float*)d_in[19];
  const float* Wb0  = (const float*)d_in[20];
  const float* Ww1  = (const float*)d_in[21];
  const float* Wb1  = (const float*)d_in[22];
  const float* Ww2  = (const float*)d_in[23];
  const float* Wb2  = (const float*)d_in[24];
  const float* r1   = (const float*)d_in[25];
  const float* r2   = (const float*)d_in[26];
  const float* r3   = (const float*)d_in[27];

  pc_conv<<<1024, 256, 0, stream>>>(Wih1, Whh1, Wih2, Whh2, Whh3, Vw1, Vw2, Vw3);
  pc_fold<<<2304, 256, 0, stream>>>(Wih1, Wih2, Wih3, Ww0, Ww1, Ww2);
  pc_init<<<1, NWG, 0, stream>>>();
  pc_main<<<NWG, NTH, 0, stream>>>(x, Wih1, Whh1, bih1, bhh1, Vw1, Vb1,
                                   Wih2, Whh2, bih2, bhh2, Vw2, Vb2,
                                   Wih3, Whh3, bih3, bhh3, Vw3, Vb3,
                                   Ww0, Wb0, Ww1, Wb1, Ww2, Wb2,
                                   r1, r2, r3, (float*)d_out);
}

// Round 10
// 8419.556 us; speedup vs baseline: 1.7316x; 1.7316x over previous
//
#include <hip/hip_runtime.h>
#include <math.h>

#define HD 1024
#define CD 256
#define TT 512
#define GD 4096                 // 4*H
#define NWG 256
#define NTH 1024
#define WPB 16                  // waves per block
#define NWAVE (NWG*WPB)         // 4096
#define LAMF 0.05f
#define SMEMB (4 * WPB * HD * 2)   // 128 KB dynamic LDS: M2,W2b,Whh2,M3 rows

typedef unsigned long long ull;
typedef unsigned short ushortt;
typedef _Float16 hh2 __attribute__((ext_vector_type(2)));

// ---------------- fp16 weight copies (built per call) ---------------------
__device__ __align__(16) ushortt hM1[GD * CD];    //  2 MB : Wih1[:,:H]@Ww0
__device__ __align__(16) ushortt hM2[GD * HD];    //  8 MB : Wih2[:,:H]@Ww1
__device__ __align__(16) ushortt hM3[GD * HD];    //  8 MB : Wih3@Ww2
__device__ __align__(16) ushortt hW1b[GD * HD];   //  8 MB : Wih1[:,H:]
__device__ __align__(16) ushortt hWhh1[GD * HD];  //  8 MB
__device__ __align__(16) ushortt hW2b[GD * HD];   //  8 MB : Wih2[:,H:]
__device__ __align__(16) ushortt hWhh2[GD * HD];  //  8 MB
__device__ __align__(16) ushortt hWhh3[GD * HD];  //  8 MB
__device__ __align__(16) ushortt hVw1[CD * HD];   // .5 MB
__device__ __align__(16) ushortt hVw2[HD * HD];   //  2 MB
__device__ __align__(16) ushortt hVw3[HD * HD];   //  2 MB

// ---------------- cross-WG vectors (only matvec outputs are published) ----
__device__ __align__(16) float d_g1[GD], d_g2[GD], d_g3[GD];
__device__ __align__(16) float d_z1[CD];
__device__ __align__(16) float d_rec2[HD], d_rec3[HD];
__device__ int d_arr[NWG][32];
__device__ int d_rel;

__global__ void pc_init() { d_arr[threadIdx.x][0] = 0; if (threadIdx.x == 0) d_rel = 0; }

__device__ __forceinline__ float sigf(float x)     { return 1.f / (1.f + __expf(-x)); }
__device__ __forceinline__ float tanhfast(float x) { return 1.f - 2.f / (1.f + __expf(2.f * x)); }

__device__ __forceinline__ ushortt f2h(float x) {
  union { ushortt u; _Float16 h; } c; c.h = (_Float16)x; return c.u;
}
__device__ __forceinline__ float h2f(ushortt u) {
  union { ushortt u; _Float16 h; } c; c.u = u; return (float)c.h;
}
__device__ __forceinline__ unsigned packh2(float a, float b) {
  union { unsigned u; hh2 h; } c; c.h = hh2{(_Float16)a, (_Float16)b}; return c.u;
}
__device__ __forceinline__ float fd2(unsigned a, unsigned b, float c) {
  union { unsigned u; hh2 h; } ua, ub; ua.u = a; ub.u = b;
  return __builtin_amdgcn_fdot2(ua.h, ub.h, c, false);
}

__device__ __forceinline__ float cload(const float* p) {
  return __hip_atomic_load(p, __ATOMIC_RELAXED, __HIP_MEMORY_SCOPE_AGENT);
}
__device__ __forceinline__ void cstore(float* p, float v) {
  __hip_atomic_store(p, v, __ATOMIC_RELAXED, __HIP_MEMORY_SCOPE_AGENT);
}
__device__ __forceinline__ float2 cload2(const float* p) {
  union { ull u; float2 f; } c;
  c.u = __hip_atomic_load((const ull*)p, __ATOMIC_RELAXED, __HIP_MEMORY_SCOPE_AGENT);
  return c.f;
}

// Distributed epoch barrier (R3-proven; no cache-invalidating fences).
__device__ __forceinline__ void gbar(int& ep) {
  ++ep;
  __syncthreads();
  const int tid = threadIdx.x;
  if (blockIdx.x == 0) {
    if (tid >= 1 && tid < NWG) {
      while (__hip_atomic_load(&d_arr[tid][0], __ATOMIC_RELAXED, __HIP_MEMORY_SCOPE_AGENT) < ep)
        __builtin_amdgcn_s_sleep(1);
    }
    __syncthreads();
    if (tid == 0)
      __hip_atomic_store(&d_rel, ep, __ATOMIC_RELEASE, __HIP_MEMORY_SCOPE_AGENT);
  } else {
    if (tid == 0) {
      __hip_atomic_store(&d_arr[blockIdx.x][0], ep, __ATOMIC_RELEASE, __HIP_MEMORY_SCOPE_AGENT);
      while (__hip_atomic_load(&d_rel, __ATOMIC_RELAXED, __HIP_MEMORY_SCOPE_AGENT) < ep)
        __builtin_amdgcn_s_sleep(1);
    }
    __syncthreads();
  }
}

__device__ __forceinline__ float wredsum(float v) {
  #pragma unroll
  for (int off = 32; off; off >>= 1) v += __shfl_xor(v, off);
  return v;
}
__device__ __forceinline__ float wredmax(float v) {
  #pragma unroll
  for (int off = 32; off; off >>= 1) v = fmaxf(v, __shfl_xor(v, off));
  return v;
}

// fp32 dot (prologue only)
__device__ __forceinline__ float dotp(const float* __restrict__ w, const float* xv, int n, int lane) {
  float a0 = 0.f, a1 = 0.f, a2 = 0.f, a3 = 0.f;
  for (int c = lane * 4; c < n; c += 256) {
    const float4 wv = *(const float4*)(w + c);
    const float4 vv = *(const float4*)(xv + c);
    a0 = fmaf(wv.x, vv.x, a0); a1 = fmaf(wv.y, vv.y, a1);
    a2 = fmaf(wv.z, vv.z, a2); a3 = fmaf(wv.w, vv.w, a3);
  }
  return (a0 + a1) + (a2 + a3);
}

// fp16 dot over 1024 halves (weight row pointer: global OR LDS; compiler
// infers the address space after inlining)
__device__ __forceinline__ float dotH(const ushortt* __restrict__ w, const ushortt* xv, int lane) {
  const uint4 w0 = *(const uint4*)(w + lane * 8);
  const uint4 w1 = *(const uint4*)(w + lane * 8 + 512);
  const uint4 v0 = *(const uint4*)(xv + lane * 8);
  const uint4 v1 = *(const uint4*)(xv + lane * 8 + 512);
  float a = 0.f;
  a = fd2(w0.x, v0.x, a); a = fd2(w0.y, v0.y, a);
  a = fd2(w0.z, v0.z, a); a = fd2(w0.w, v0.w, a);
  a = fd2(w1.x, v1.x, a); a = fd2(w1.y, v1.y, a);
  a = fd2(w1.z, v1.z, a); a = fd2(w1.w, v1.w, a);
  return a;
}
// fp16 dot over 256 halves
__device__ __forceinline__ float dotH256(const ushortt* __restrict__ w, const ushortt* xv, int lane) {
  const uint2 wv = *(const uint2*)(w + lane * 4);
  const uint2 vv = *(const uint2*)(xv + lane * 4);
  float a = fd2(wv.x, vv.x, 0.f);
  return fd2(wv.y, vv.y, a);
}

// ---------------- fp32->fp16 weight conversion ----------------------------
__global__ __launch_bounds__(256) void pc_conv(
    const float* __restrict__ Wih1, const float* __restrict__ Whh1,
    const float* __restrict__ Wih2, const float* __restrict__ Whh2,
    const float* __restrict__ Whh3, const float* __restrict__ Vw1,
    const float* __restrict__ Vw2,  const float* __restrict__ Vw3) {
  const size_t stride = (size_t)gridDim.x * 256;
  const size_t i0 = (size_t)blockIdx.x * 256 + threadIdx.x;
  for (size_t i = i0; i < (size_t)GD * HD; i += stride) {
    size_t r = i >> 10, c = i & 1023;
    size_t src = (r << 11) + HD + c;
    hW1b[i]  = f2h(Wih1[src]);
    hW2b[i]  = f2h(Wih2[src]);
    hWhh1[i] = f2h(Whh1[i]);
    hWhh2[i] = f2h(Whh2[i]);
    hWhh3[i] = f2h(Whh3[i]);
  }
  for (size_t i = i0; i < (size_t)HD * HD; i += stride) {
    hVw2[i] = f2h(Vw2[i]);
    hVw3[i] = f2h(Vw3[i]);
  }
  for (size_t i = i0; i < (size_t)CD * HD; i += stride) hVw1[i] = f2h(Vw1[i]);
}

// ---------------- fold GEMM: fp16 C[4096 x N] = A @ B ---------------------
__global__ __launch_bounds__(256) void pc_fold(
    const float* __restrict__ Wih1, const float* __restrict__ Wih2,
    const float* __restrict__ Wih3, const float* __restrict__ Ww0,
    const float* __restrict__ Ww1,  const float* __restrict__ Ww2) {
  int b = blockIdx.x;
  const float* A; const float* B; ushortt* C; int N, lda;
  if (b < 256)        { A = Wih1; B = Ww0; C = hM1; N = CD; lda = 2 * HD; }
  else if (b < 1280)  { A = Wih2; B = Ww1; C = hM2; N = HD; lda = 2 * HD; b -= 256; }
  else                { A = Wih3; B = Ww2; C = hM3; N = HD; lda = HD;     b -= 1280; }
  const int ctiles = N >> 6;
  const int rt = b / ctiles, ct = b - rt * ctiles;
  const int tid = threadIdx.x;
  const int tx = tid & 15, ty = tid >> 4;

  __shared__ float sA[16][65];
  __shared__ float sB[16][64];

  float acc[4][4] = {};
  const int ar = tid >> 2, aq = tid & 3;
  const int br = tid >> 4, bq = tid & 15;

  for (int kk = 0; kk < HD; kk += 16) {
    float4 av = *(const float4*)(A + (size_t)(rt * 64 + ar) * lda + kk + aq * 4);
    float4 bv = *(const float4*)(B + (size_t)(kk + br) * N + ct * 64 + bq * 4);
    __syncthreads();
    sA[aq * 4 + 0][ar] = av.x; sA[aq * 4 + 1][ar] = av.y;
    sA[aq * 4 + 2][ar] = av.z; sA[aq * 4 + 3][ar] = av.w;
    *(float4*)&sB[br][bq * 4] = bv;
    __syncthreads();
    #pragma unroll
    for (int k = 0; k < 16; ++k) {
      const float4 b4 = *(const float4*)&sB[k][tx * 4];
      const float a0 = sA[k][ty * 4 + 0], a1 = sA[k][ty * 4 + 1];
      const float a2 = sA[k][ty * 4 + 2], a3 = sA[k][ty * 4 + 3];
      acc[0][0] = fmaf(a0, b4.x, acc[0][0]); acc[0][1] = fmaf(a0, b4.y, acc[0][1]);
      acc[0][2] = fmaf(a0, b4.z, acc[0][2]); acc[0][3] = fmaf(a0, b4.w, acc[0][3]);
      acc[1][0] = fmaf(a1, b4.x, acc[1][0]); acc[1][1] = fmaf(a1, b4.y, acc[1][1]);
      acc[1][2] = fmaf(a1, b4.z, acc[1][2]); acc[1][3] = fmaf(a1, b4.w, acc[1][3]);
      acc[2][0] = fmaf(a2, b4.x, acc[2][0]); acc[2][1] = fmaf(a2, b4.y, acc[2][1]);
      acc[2][2] = fmaf(a2, b4.z, acc[2][2]); acc[2][3] = fmaf(a2, b4.w, acc[2][3]);
      acc[3][0] = fmaf(a3, b4.x, acc[3][0]); acc[3][1] = fmaf(a3, b4.y, acc[3][1]);
      acc[3][2] = fmaf(a3, b4.z, acc[3][2]); acc[3][3] = fmaf(a3, b4.w, acc[3][3]);
    }
  }
  #pragma unroll
  for (int i = 0; i < 4; ++i) {
    uint2 r = make_uint2(packh2(acc[i][0], acc[i][1]), packh2(acc[i][2], acc[i][3]));
    *(uint2*)(C + (size_t)(rt * 64 + ty * 4 + i) * N + ct * 64 + tx * 4) = r;
  }
}

__global__ __launch_bounds__(NTH, 1) void pc_main(
    const float* __restrict__ x,
    const float* __restrict__ Wih1, const float* __restrict__ Whh1,
    const float* __restrict__ bih1, const float* __restrict__ bhh1,
    const float* __restrict__ Vw1,  const float* __restrict__ Vb1,
    const float* __restrict__ Wih2, const float* __restrict__ Whh2,
    const float* __restrict__ bih2, const float* __restrict__ bhh2,
    const float* __restrict__ Vw2,  const float* __restrict__ Vb2,
    const float* __restrict__ Wih3, const float* __restrict__ Whh3,
    const float* __restrict__ bih3, const float* __restrict__ bhh3,
    const float* __restrict__ Vw3,  const float* __restrict__ Vb3,
    const float* __restrict__ Ww0,  const float* __restrict__ Wb0,
    const float* __restrict__ Ww1,  const float* __restrict__ Wb1,
    const float* __restrict__ Ww2,  const float* __restrict__ Wb2,
    const float* __restrict__ r1,   const float* __restrict__ r2,
    const float* __restrict__ r3,
    float* __restrict__ out) {
  const int tid  = threadIdx.x;
  const int lane = tid & 63;
  const int bid  = blockIdx.x;
  const int wv   = tid >> 6;            // wave index within block
  const int wid  = bid * WPB + wv;
  const bool iswg0 = (bid == 0);
  const bool w0    = iswg0 && tid < 64;

  // dynamic LDS: per-wave private rows of M2, W2b, Whh2 (P) and M3 (Q)
  extern __shared__ __align__(16) ushortt smem[];
  ushortt* sM2 = smem;                  // [WPB][HD]
  ushortt* sW2 = sM2 + WPB * HD;
  ushortt* sH2 = sW2 + WPB * HD;
  ushortt* sM3 = sH2 + WPB * HD;

  // per-WG local state: activations fp16 (matvec operands), cell states fp32
  __shared__ __align__(16) ushortt s_h1[HD], s_TD1[HD], s_h2[HD], s_TD2[HD], s_h3[HD];
  __shared__ __align__(16) float s_c1[HD], s_c2[HD], s_c3[HD];
  __shared__ __align__(16) ushortt s_small[CD];   // TD0 feeding next g1

  const int e = (tid < 512) ? (((tid + (bid << 3)) & 511) * 2) : 0;

  const int jR = ((wid & 3) == 1)  ? (wid >> 2) : -1;   // rec3 (P) / rec2 (Q)
  const int jZ = ((wid & 15) == 2) ? (wid >> 4) : -1;   // z1 (P)

  int ep = 0;
  float loss_acc = 0.f, fll_acc = 0.f;
  float b1, b2, b3, vbR3 = 0.f, vbR2 = 0.f, vbZ = 0.f;

  // ---------------- prologue: LDS weight fill, fold biases, init, g1(0) ----
  {
    // copy this wave's rows into LDS (rows are wave-private forever after)
    const uint4* gM2 = (const uint4*)(hM2   + (size_t)wid * HD);
    const uint4* gW2 = (const uint4*)(hW2b  + (size_t)wid * HD);
    const uint4* gH2 = (const uint4*)(hWhh2 + (size_t)wid * HD);
    const uint4* gM3 = (const uint4*)(hM3   + (size_t)wid * HD);
    uint4* lM2 = (uint4*)(sM2 + wv * HD);
    uint4* lW2 = (uint4*)(sW2 + wv * HD);
    uint4* lH2 = (uint4*)(sH2 + wv * HD);
    uint4* lM3 = (uint4*)(sM3 + wv * HD);
    #pragma unroll
    for (int i = 0; i < 2; ++i) {
      lM2[lane + 64 * i] = gM2[lane + 64 * i];
      lW2[lane + 64 * i] = gW2[lane + 64 * i];
      lH2[lane + 64 * i] = gH2[lane + 64 * i];
      lM3[lane + 64 * i] = gM3[lane + 64 * i];
    }
  }
  if (tid < 512) {
    int j = tid * 2;
    *(float2*)(s_c1 + j) = *(const float2*)(Wb0 + j);
    *(float2*)(s_c2 + j) = *(const float2*)(Wb1 + j);
    *(float2*)(s_c3 + j) = *(const float2*)(Wb2 + j);
  }
  __syncthreads();
  b1 = bih1[wid] + bhh1[wid] + wredsum(dotp(Wih1 + (size_t)wid * 2 * HD, s_c1, HD, lane));
  b2 = bih2[wid] + bhh2[wid] + wredsum(dotp(Wih2 + (size_t)wid * 2 * HD, s_c2, HD, lane));
  b3 = bih3[wid] + bhh3[wid] + wredsum(dotp(Wih3 + (size_t)wid * HD,     s_c3, HD, lane));
  if (jR >= 0) { vbR3 = Vb3[jR]; vbR2 = Vb2[jR]; }
  if (jZ >= 0) vbZ = Vb1[jZ];
  __syncthreads();
  if (tid < 512) {
    int j = tid * 2;
    const float2 z2 = make_float2(0.f, 0.f);
    *(float2*)(s_c1 + j) = z2; *(float2*)(s_c2 + j) = z2; *(float2*)(s_c3 + j) = z2;
    *(unsigned*)(s_h1 + j) = 0u; *(unsigned*)(s_TD1 + j) = 0u;
    *(unsigned*)(s_h2 + j) = 0u; *(unsigned*)(s_TD2 + j) = 0u;
    *(unsigned*)(s_h3 + j) = 0u;
  }
  if (tid < 64) {                       // softmax(r1) -> TD0(0); loss0(0)
    float4 z4 = *(const float4*)(r1 + tid * 4);
    float m = wredmax(fmaxf(fmaxf(z4.x, z4.y), fmaxf(z4.z, z4.w)));
    float e0 = __expf(z4.x - m), e1 = __expf(z4.y - m);
    float e2 = __expf(z4.z - m), e3 = __expf(z4.w - m);
    float inv = 1.f / wredsum((e0 + e1) + (e2 + e3));
    float p0 = e0 * inv, p1 = e1 * inv, p2 = e2 * inv, p3 = e3 * inv;
    float4 xv = *(const float4*)(x + tid * 4);
    *(uint2*)(s_small + tid * 4) =
        make_uint2(packh2(xv.x - p0, xv.y - p1), packh2(xv.z - p2, xv.w - p3));
    if (iswg0) {
      float u = xv.x * __logf(p0) + (1.f - xv.x) * __logf(1.f - p0)
              + xv.y * __logf(p1) + (1.f - xv.y) * __logf(1.f - p1)
              + xv.z * __logf(p2) + (1.f - xv.z) * __logf(1.f - p2)
              + xv.w * __logf(p3) + (1.f - xv.w) * __logf(1.f - p3);
      u = wredsum(u);
      if (tid == 0) { loss_acc -= u; fll_acc -= u; }
    }
  }
  __syncthreads();
  {                                     // g1(0) = M1@TD0(0) + b1
    float s = wredsum(dotH256(hM1 + (size_t)wid * CD, s_small, lane));
    if (lane == 0) cstore(&d_g1[wid], s + b1);
  }
  gbar(ep);

  for (int t = 0; t < TT; ++t) {
    // ========== P(t): cell3(t-1), cell1(t) ; g2(t), z1(t), rec3(t-1) ======
    if (tid < 512) {
      if (t > 0) {                      // cell3(t-1)
        float2 gi = cload2(&d_g3[e]),          gf = cload2(&d_g3[e + HD]);
        float2 gg = cload2(&d_g3[e + 2 * HD]), go = cload2(&d_g3[e + 3 * HD]);
        float cA = sigf(gf.x) * s_c3[e]     + sigf(gi.x) * tanhfast(gg.x);
        float cB = sigf(gf.y) * s_c3[e + 1] + sigf(gi.y) * tanhfast(gg.y);
        float hA = sigf(go.x) * tanhfast(cA);
        float hB = sigf(go.y) * tanhfast(cB);
        s_c3[e] = cA; s_c3[e + 1] = cB;
        *(unsigned*)(s_h3 + e) = packh2(hA, hB);
      }
      {                                 // cell1(t)
        float2 gi = cload2(&d_g1[e]),          gf = cload2(&d_g1[e + HD]);
        float2 gg = cload2(&d_g1[e + 2 * HD]), go = cload2(&d_g1[e + 3 * HD]);
        float2 rc = (t == 0) ? *(const float2*)(r2 + e) : cload2(&d_rec2[e]);
        float cA = sigf(gf.x) * s_c1[e]     + sigf(gi.x) * tanhfast(gg.x);
        float cB = sigf(gf.y) * s_c1[e + 1] + sigf(gi.y) * tanhfast(gg.y);
        float hA = sigf(go.x) * tanhfast(cA);
        float hB = sigf(go.y) * tanhfast(cB);
        s_c1[e] = cA; s_c1[e + 1] = cB;
        *(unsigned*)(s_h1 + e)  = packh2(hA, hB);
        *(unsigned*)(s_TD1 + e) = packh2(hA - rc.x, hB - rc.y);
      }
    }
    __syncthreads();
    if (w0) {                           // LAM * sum|TD1(t)|
      float a = 0.f;
      #pragma unroll
      for (int k = 0; k < 16; ++k) a += fabsf(h2f(s_TD1[tid + 64 * k]));
      a = wredsum(a);
      if (tid == 0) loss_acc += LAMF * a;
    }
    {                                   // g2(t): all three rows from LDS
      float s = dotH(sM2 + wv * HD, s_TD1, lane)
              + dotH(sW2 + wv * HD, s_TD2, lane)
              + dotH(sH2 + wv * HD, s_h2,  lane);
      s = wredsum(s);
      if (lane == 0) cstore(&d_g2[wid], s + b2);
    }
    if (t > 0 && jR >= 0) {             // rec3(t-1) = Vw3 @ h3(t-1)
      float s = wredsum(dotH(hVw3 + (size_t)jR * HD, s_h3, lane));
      if (lane == 0) cstore(&d_rec3[jR], s + vbR3);
    }
    if (jZ >= 0) {                      // z1(t) = Vw1 @ h1(t)
      float s = wredsum(dotH(hVw1 + (size_t)jZ * HD, s_h1, lane));
      if (lane == 0) cstore(&d_z1[jZ], s + vbZ);
    }
    gbar(ep);

    // ========== Q(t): cell2(t), softmax(z1) ; g3(t), g1(t+1), rec2(t) =====
    if (tid < 512) {                    // cell2(t)
      float2 gi = cload2(&d_g2[e]),          gf = cload2(&d_g2[e + HD]);
      float2 gg = cload2(&d_g2[e + 2 * HD]), go = cload2(&d_g2[e + 3 * HD]);
      float2 rc = (t == 0) ? *(const float2*)(r3 + e) : cload2(&d_rec3[e]);
      float cA = sigf(gf.x) * s_c2[e]     + sigf(gi.x) * tanhfast(gg.x);
      float cB = sigf(gf.y) * s_c2[e + 1] + sigf(gi.y) * tanhfast(gg.y);
      float hA = sigf(go.x) * tanhfast(cA);
      float hB = sigf(go.y) * tanhfast(cB);
      s_c2[e] = cA; s_c2[e + 1] = cB;
      *(unsigned*)(s_h2 + e)  = packh2(hA, hB);
      *(unsigned*)(s_TD2 + e) = packh2(hA - rc.x, hB - rc.y);
    }
    if (tid < 64) {                     // softmax(z1(t)) -> predictions[t], TD0(t+1)
      float2 za = cload2(&d_z1[tid * 4]), zb = cload2(&d_z1[tid * 4 + 2]);
      float m = wredmax(fmaxf(fmaxf(za.x, za.y), fmaxf(zb.x, zb.y)));
      float e0 = __expf(za.x - m), e1 = __expf(za.y - m);
      float e2 = __expf(zb.x - m), e3 = __expf(zb.y - m);
      float inv = 1.f / wredsum((e0 + e1) + (e2 + e3));
      float p0 = e0 * inv, p1 = e1 * inv, p2 = e2 * inv, p3 = e3 * inv;
      if (t < TT - 1) {
        float4 xv = *(const float4*)(x + (size_t)(t + 1) * CD + tid * 4);
        *(uint2*)(s_small + tid * 4) =
            make_uint2(packh2(xv.x - p0, xv.y - p1), packh2(xv.z - p2, xv.w - p3));
        if (iswg0) {                    // loss0(t+1)
          float u = xv.x * __logf(p0) + (1.f - xv.x) * __logf(1.f - p0)
                  + xv.y * __logf(p1) + (1.f - xv.y) * __logf(1.f - p1)
                  + xv.z * __logf(p2) + (1.f - xv.z) * __logf(1.f - p2)
                  + xv.w * __logf(p3) + (1.f - xv.w) * __logf(1.f - p3);
          u = wredsum(u);
          if (tid == 0) { loss_acc -= u; fll_acc -= u; }
        }
      }
      if (iswg0) {                      // predictions[t]
        float* po = out + 2 + (size_t)t * CD + tid * 4;
        po[0] = p0; po[1] = p1; po[2] = p2; po[3] = p3;
      }
    }
    __syncthreads();
    if (w0) {                           // LAM^2 * sum|TD2(t)|
      float a = 0.f;
      #pragma unroll
      for (int k = 0; k < 16; ++k) a += fabsf(h2f(s_TD2[tid + 64 * k]));
      a = wredsum(a);
      if (tid == 0) loss_acc += (LAMF * LAMF) * a;
    }
    if (t < TT - 1) {
      {                                 // g3(t): M3 from LDS, Whh3 from L2
        float s = dotH(sM3 + wv * HD, s_TD2, lane)
                + dotH(hWhh3 + (size_t)wid * HD, s_h3, lane);
        s = wredsum(s);
        if (lane == 0) cstore(&d_g3[wid], s + b3);
      }
      {                                 // g1(t+1): W1b/Whh1/M1 from L2
        float s = dotH256(hM1 + (size_t)wid * CD, s_small, lane)
                + dotH(hW1b  + (size_t)wid * HD, s_TD1, lane)
                + dotH(hWhh1 + (size_t)wid * HD, s_h1,  lane);
        s = wredsum(s);
        if (lane == 0) cstore(&d_g1[wid], s + b1);
      }
      if (jR >= 0) {                    // rec2(t) = Vw2 @ h2(t)
        float s = wredsum(dotH(hVw2 + (size_t)jR * HD, s_h2, lane));
        if (lane == 0) cstore(&d_rec2[jR], s + vbR2);
      }
      gbar(ep);
    }
  }

  if (iswg0 && tid == 0) { out[0] = loss_acc; out[1] = fll_acc; }
}

extern "C" void kernel_launch(void* const* d_in, const int* in_sizes, int n_in,
                              void* d_out, int out_size, void* d_ws, size_t ws_size,
                              hipStream_t stream) {
  const float* x    = (const float*)d_in[0];
  const float* Wih1 = (const float*)d_in[1];
  const float* Whh1 = (const float*)d_in[2];
  const float* bih1 = (const float*)d_in[3];
  const float* bhh1 = (const float*)d_in[4];
  const float* Vw1  = (const float*)d_in[5];
  const float* Vb1  = (const float*)d_in[6];
  const float* Wih2 = (const float*)d_in[7];
  const float* Whh2 = (const float*)d_in[8];
  const float* bih2 = (const float*)d_in[9];
  const float* bhh2 = (const float*)d_in[10];
  const float* Vw2  = (const float*)d_in[11];
  const float* Vb2  = (const float*)d_in[12];
  const float* Wih3 = (const float*)d_in[13];
  const float* Whh3 = (const float*)d_in[14];
  const float* bih3 = (const float*)d_in[15];
  const float* bhh3 = (const float*)d_in[16];
  const float* Vw3  = (const float*)d_in[17];
  const float* Vb3  = (const float*)d_in[18];
  const float* Ww0  = (const float*)d_in[19];
  const float* Wb0  = (const float*)d_in[20];
  const float* Ww1  = (const float*)d_in[21];
  const float* Wb1  = (const float*)d_in[22];
  const float* Ww2  = (const float*)d_in[23];
  const float* Wb2  = (const float*)d_in[24];
  const float* r1   = (const float*)d_in[25];
  const float* r2   = (const float*)d_in[26];
  const float* r3   = (const float*)d_in[27];

  static int smem_set = 0;
  if (!smem_set) {
    hipFuncSetAttribute((const void*)pc_main,
                        hipFuncAttributeMaxDynamicSharedMemorySize, SMEMB);
    smem_set = 1;
  }

  pc_conv<<<1024, 256, 0, stream>>>(Wih1, Whh1, Wih2, Whh2, Whh3, Vw1, Vw2, Vw3);
  pc_fold<<<2304, 256, 0, stream>>>(Wih1, Wih2, Wih3, Ww0, Ww1, Ww2);
  pc_init<<<1, NWG, 0, stream>>>();
  pc_main<<<NWG, NTH, SMEMB, stream>>>(x, Wih1, Whh1, bih1, bhh1, Vw1, Vb1,
                                       Wih2, Whh2, bih2, bhh2, Vw2, Vb2,
                                       Wih3, Whh3, bih3, bhh3, Vw3, Vb3,
                                       Ww0, Wb0, Ww1, Wb1, Ww2, Wb2,
                                       r1, r2, r3, (float*)d_out);
}

// Round 11
// 7692.418 us; speedup vs baseline: 1.8953x; 1.0945x over previous
//
#include <hip/hip_runtime.h>
#include <math.h>

#define HD 1024
#define CD 256
#define TT 512
#define GD 4096                 // 4*H
#define NWG 256
#define NTH 1024
#define WPB 16                  // waves per block
#define LAMF 0.05f
#define SMEMB (4 * WPB * HD * 2)   // 128 KB dynamic LDS: M2,W2b,Whh2,M3 rows

typedef unsigned long long ull;
typedef unsigned short ushortt;
typedef _Float16 hh2 __attribute__((ext_vector_type(2)));

// ---------------- fp16 weight copies (built per call) ---------------------
__device__ __align__(16) ushortt hM1[GD * CD];    //  2 MB : Wih1[:,:H]@Ww0
__device__ __align__(16) ushortt hM2[GD * HD];    //  8 MB : Wih2[:,:H]@Ww1
__device__ __align__(16) ushortt hM3[GD * HD];    //  8 MB : Wih3@Ww2
__device__ __align__(16) ushortt hW1b[GD * HD];   //  8 MB : Wih1[:,H:]
__device__ __align__(16) ushortt hWhh1[GD * HD];  //  8 MB
__device__ __align__(16) ushortt hW2b[GD * HD];   //  8 MB : Wih2[:,H:]
__device__ __align__(16) ushortt hWhh2[GD * HD];  //  8 MB
__device__ __align__(16) ushortt hWhh3[GD * HD];  //  8 MB
__device__ __align__(16) ushortt hVw1[CD * HD];   // .5 MB
__device__ __align__(16) ushortt hVw2[HD * HD];   //  2 MB
__device__ __align__(16) ushortt hVw3[HD * HD];   //  2 MB

// ---------------- published cross-WG state (fp16 vectors + z1) ------------
__device__ __align__(8) ushortt d_h1h[HD], d_TD1h[HD], d_h3h[HD];
__device__ __align__(8) ushortt d_h2h[2][HD], d_TD2h[2][HD];   // parity dbuf
__device__ __align__(16) float d_z1[CD];
__device__ int d_arr[NWG][32];
__device__ int d_rel;

__global__ void pc_init() { d_arr[threadIdx.x][0] = 0; if (threadIdx.x == 0) d_rel = 0; }

__device__ __forceinline__ float sigf(float x)     { return 1.f / (1.f + __expf(-x)); }
__device__ __forceinline__ float tanhfast(float x) { return 1.f - 2.f / (1.f + __expf(2.f * x)); }

__device__ __forceinline__ ushortt f2h(float x) {
  union { ushortt u; _Float16 h; } c; c.h = (_Float16)x; return c.u;
}
__device__ __forceinline__ float h2f(ushortt u) {
  union { ushortt u; _Float16 h; } c; c.u = u; return (float)c.h;
}
__device__ __forceinline__ unsigned packh2(float a, float b) {
  union { unsigned u; hh2 h; } c; c.h = hh2{(_Float16)a, (_Float16)b}; return c.u;
}
__device__ __forceinline__ float fd2(unsigned a, unsigned b, float c) {
  union { unsigned u; hh2 h; } ua, ub; ua.u = a; ub.u = b;
  return __builtin_amdgcn_fdot2(ua.h, ub.h, c, false);
}

__device__ __forceinline__ float cload(const float* p) {
  return __hip_atomic_load(p, __ATOMIC_RELAXED, __HIP_MEMORY_SCOPE_AGENT);
}
__device__ __forceinline__ void cstore(float* p, float v) {
  __hip_atomic_store(p, v, __ATOMIC_RELAXED, __HIP_MEMORY_SCOPE_AGENT);
}
__device__ __forceinline__ float2 cload2(const float* p) {
  union { ull u; float2 f; } c;
  c.u = __hip_atomic_load((const ull*)p, __ATOMIC_RELAXED, __HIP_MEMORY_SCOPE_AGENT);
  return c.f;
}
__device__ __forceinline__ uint2 cloadU2(const ushortt* p) {
  union { ull u; uint2 v; } c;
  c.u = __hip_atomic_load((const ull*)p, __ATOMIC_RELAXED, __HIP_MEMORY_SCOPE_AGENT);
  return c.v;
}
__device__ __forceinline__ void cstoreU2(ushortt* p, uint2 v) {
  union { ull u; uint2 v; } c; c.v = v;
  __hip_atomic_store((ull*)p, c.u, __ATOMIC_RELAXED, __HIP_MEMORY_SCOPE_AGENT);
}

// Distributed epoch barrier (R3-proven; no cache-invalidating fences).
__device__ __forceinline__ void gbar(int& ep) {
  ++ep;
  __syncthreads();
  const int tid = threadIdx.x;
  if (blockIdx.x == 0) {
    if (tid >= 1 && tid < NWG) {
      while (__hip_atomic_load(&d_arr[tid][0], __ATOMIC_RELAXED, __HIP_MEMORY_SCOPE_AGENT) < ep)
        __builtin_amdgcn_s_sleep(1);
    }
    __syncthreads();
    if (tid == 0)
      __hip_atomic_store(&d_rel, ep, __ATOMIC_RELEASE, __HIP_MEMORY_SCOPE_AGENT);
  } else {
    if (tid == 0) {
      __hip_atomic_store(&d_arr[blockIdx.x][0], ep, __ATOMIC_RELEASE, __HIP_MEMORY_SCOPE_AGENT);
      while (__hip_atomic_load(&d_rel, __ATOMIC_RELAXED, __HIP_MEMORY_SCOPE_AGENT) < ep)
        __builtin_amdgcn_s_sleep(1);
    }
    __syncthreads();
  }
}

__device__ __forceinline__ float wredsum(float v) {
  #pragma unroll
  for (int off = 32; off; off >>= 1) v += __shfl_xor(v, off);
  return v;
}
__device__ __forceinline__ float wredmax(float v) {
  #pragma unroll
  for (int off = 32; off; off >>= 1) v = fmaxf(v, __shfl_xor(v, off));
  return v;
}

// fp32 dot (prologue only)
__device__ __forceinline__ float dotp(const float* __restrict__ w, const float* xv, int n, int lane) {
  float a0 = 0.f, a1 = 0.f, a2 = 0.f, a3 = 0.f;
  for (int c = lane * 4; c < n; c += 256) {
    const float4 wv = *(const float4*)(w + c);
    const float4 vv = *(const float4*)(xv + c);
    a0 = fmaf(wv.x, vv.x, a0); a1 = fmaf(wv.y, vv.y, a1);
    a2 = fmaf(wv.z, vv.z, a2); a3 = fmaf(wv.w, vv.w, a3);
  }
  return (a0 + a1) + (a2 + a3);
}

// fp16 dot over 1024 halves (weight row pointer: global OR LDS)
__device__ __forceinline__ float dotH(const ushortt* __restrict__ w, const ushortt* xv, int lane) {
  const uint4 w0 = *(const uint4*)(w + lane * 8);
  const uint4 w1 = *(const uint4*)(w + lane * 8 + 512);
  const uint4 v0 = *(const uint4*)(xv + lane * 8);
  const uint4 v1 = *(const uint4*)(xv + lane * 8 + 512);
  float a = 0.f;
  a = fd2(w0.x, v0.x, a); a = fd2(w0.y, v0.y, a);
  a = fd2(w0.z, v0.z, a); a = fd2(w0.w, v0.w, a);
  a = fd2(w1.x, v1.x, a); a = fd2(w1.y, v1.y, a);
  a = fd2(w1.z, v1.z, a); a = fd2(w1.w, v1.w, a);
  return a;
}
// fp16 dot over 256 halves
__device__ __forceinline__ float dotH256(const ushortt* __restrict__ w, const ushortt* xv, int lane) {
  const uint2 wv = *(const uint2*)(w + lane * 4);
  const uint2 vv = *(const uint2*)(xv + lane * 4);
  float a = fd2(wv.x, vv.x, 0.f);
  return fd2(wv.y, vv.y, a);
}

// ---------------- fp32->fp16 weight conversion ----------------------------
__global__ __launch_bounds__(256) void pc_conv(
    const float* __restrict__ Wih1, const float* __restrict__ Whh1,
    const float* __restrict__ Wih2, const float* __restrict__ Whh2,
    const float* __restrict__ Whh3, const float* __restrict__ Vw1,
    const float* __restrict__ Vw2,  const float* __restrict__ Vw3) {
  const size_t stride = (size_t)gridDim.x * 256;
  const size_t i0 = (size_t)blockIdx.x * 256 + threadIdx.x;
  for (size_t i = i0; i < (size_t)GD * HD; i += stride) {
    size_t r = i >> 10, c = i & 1023;
    size_t src = (r << 11) + HD + c;
    hW1b[i]  = f2h(Wih1[src]);
    hW2b[i]  = f2h(Wih2[src]);
    hWhh1[i] = f2h(Whh1[i]);
    hWhh2[i] = f2h(Whh2[i]);
    hWhh3[i] = f2h(Whh3[i]);
  }
  for (size_t i = i0; i < (size_t)HD * HD; i += stride) {
    hVw2[i] = f2h(Vw2[i]);
    hVw3[i] = f2h(Vw3[i]);
  }
  for (size_t i = i0; i < (size_t)CD * HD; i += stride) hVw1[i] = f2h(Vw1[i]);
}

// ---------------- fold GEMM: fp16 C[4096 x N] = A @ B ---------------------
__global__ __launch_bounds__(256) void pc_fold(
    const float* __restrict__ Wih1, const float* __restrict__ Wih2,
    const float* __restrict__ Wih3, const float* __restrict__ Ww0,
    const float* __restrict__ Ww1,  const float* __restrict__ Ww2) {
  int b = blockIdx.x;
  const float* A; const float* B; ushortt* C; int N, lda;
  if (b < 256)        { A = Wih1; B = Ww0; C = hM1; N = CD; lda = 2 * HD; }
  else if (b < 1280)  { A = Wih2; B = Ww1; C = hM2; N = HD; lda = 2 * HD; b -= 256; }
  else                { A = Wih3; B = Ww2; C = hM3; N = HD; lda = HD;     b -= 1280; }
  const int ctiles = N >> 6;
  const int rt = b / ctiles, ct = b - rt * ctiles;
  const int tid = threadIdx.x;
  const int tx = tid & 15, ty = tid >> 4;

  __shared__ float sA[16][65];
  __shared__ float sB[16][64];

  float acc[4][4] = {};
  const int ar = tid >> 2, aq = tid & 3;
  const int br = tid >> 4, bq = tid & 15;

  for (int kk = 0; kk < HD; kk += 16) {
    float4 av = *(const float4*)(A + (size_t)(rt * 64 + ar) * lda + kk + aq * 4);
    float4 bv = *(const float4*)(B + (size_t)(kk + br) * N + ct * 64 + bq * 4);
    __syncthreads();
    sA[aq * 4 + 0][ar] = av.x; sA[aq * 4 + 1][ar] = av.y;
    sA[aq * 4 + 2][ar] = av.z; sA[aq * 4 + 3][ar] = av.w;
    *(float4*)&sB[br][bq * 4] = bv;
    __syncthreads();
    #pragma unroll
    for (int k = 0; k < 16; ++k) {
      const float4 b4 = *(const float4*)&sB[k][tx * 4];
      const float a0 = sA[k][ty * 4 + 0], a1 = sA[k][ty * 4 + 1];
      const float a2 = sA[k][ty * 4 + 2], a3 = sA[k][ty * 4 + 3];
      acc[0][0] = fmaf(a0, b4.x, acc[0][0]); acc[0][1] = fmaf(a0, b4.y, acc[0][1]);
      acc[0][2] = fmaf(a0, b4.z, acc[0][2]); acc[0][3] = fmaf(a0, b4.w, acc[0][3]);
      acc[1][0] = fmaf(a1, b4.x, acc[1][0]); acc[1][1] = fmaf(a1, b4.y, acc[1][1]);
      acc[1][2] = fmaf(a1, b4.z, acc[1][2]); acc[1][3] = fmaf(a1, b4.w, acc[1][3]);
      acc[2][0] = fmaf(a2, b4.x, acc[2][0]); acc[2][1] = fmaf(a2, b4.y, acc[2][1]);
      acc[2][2] = fmaf(a2, b4.z, acc[2][2]); acc[2][3] = fmaf(a2, b4.w, acc[2][3]);
      acc[3][0] = fmaf(a3, b4.x, acc[3][0]); acc[3][1] = fmaf(a3, b4.y, acc[3][1]);
      acc[3][2] = fmaf(a3, b4.z, acc[3][2]); acc[3][3] = fmaf(a3, b4.w, acc[3][3]);
    }
  }
  #pragma unroll
  for (int i = 0; i < 4; ++i) {
    uint2 r = make_uint2(packh2(acc[i][0], acc[i][1]), packh2(acc[i][2], acc[i][3]));
    *(uint2*)(C + (size_t)(rt * 64 + ty * 4 + i) * N + ct * 64 + tx * 4) = r;
  }
}

__global__ __launch_bounds__(NTH, 1) void pc_main(
    const float* __restrict__ x,
    const float* __restrict__ Wih1, const float* __restrict__ Whh1,
    const float* __restrict__ bih1, const float* __restrict__ bhh1,
    const float* __restrict__ Vw1,  const float* __restrict__ Vb1,
    const float* __restrict__ Wih2, const float* __restrict__ Whh2,
    const float* __restrict__ bih2, const float* __restrict__ bhh2,
    const float* __restrict__ Vw2,  const float* __restrict__ Vb2,
    const float* __restrict__ Wih3, const float* __restrict__ Whh3,
    const float* __restrict__ bih3, const float* __restrict__ bhh3,
    const float* __restrict__ Vw3,  const float* __restrict__ Vb3,
    const float* __restrict__ Ww0,  const float* __restrict__ Wb0,
    const float* __restrict__ Ww1,  const float* __restrict__ Wb1,
    const float* __restrict__ Ww2,  const float* __restrict__ Wb2,
    const float* __restrict__ r1,   const float* __restrict__ r2,
    const float* __restrict__ r3,
    float* __restrict__ out) {
  const int tid  = threadIdx.x;
  const int lane = tid & 63;
  const int bid  = blockIdx.x;
  const int wv   = tid >> 6;            // wave index within block
  const int gi   = wv & 3;              // gate index (i,f,g,o)
  const int slot = wv >> 2;             // owned-element slot 0..3
  const int rg   = gi * HD + bid * 4 + slot;   // this wave's gate row
  const int jown = bid * 4 + slot;      // element for rec/z rows
  const bool iswg0 = (bid == 0);
  const bool w0    = iswg0 && tid < 64;

  // dynamic LDS: per-wave private weight rows (new mapping rg)
  extern __shared__ __align__(16) ushortt smem[];
  ushortt* sM2 = smem;                  // [WPB][HD]
  ushortt* sW2 = sM2 + WPB * HD;
  ushortt* sH2 = sW2 + WPB * HD;
  ushortt* sM3 = sH2 + WPB * HD;

  // block-local vectors (fp16) + tiny cell state
  __shared__ __align__(16) ushortt s_TD1[HD], s_h1[HD], s_TD2[HD], s_h2[HD], s_h3[HD];
  __shared__ __align__(16) ushortt s_small[CD];  // TD0 feeding g1(t+1)
  __shared__ float s_gateA[WPB], s_gateB[WPB], s_rec[4];
  __shared__ float s_c1own[4], s_c2own[4], s_c3own[4];
  __shared__ __align__(16) float s_ftmp[HD];

  int ep = 0;
  float loss_acc = 0.f, fll_acc = 0.f;
  float b1, b2, b3, vbR3 = 0.f, vbR2 = 0.f, vbZ = 0.f;

  // ---------------- prologue ------------------------------------------------
  {
    // LDS weight rows (wave-private, new row mapping)
    const uint4* gM2 = (const uint4*)(hM2   + (size_t)rg * HD);
    const uint4* gW2 = (const uint4*)(hW2b  + (size_t)rg * HD);
    const uint4* gH2 = (const uint4*)(hWhh2 + (size_t)rg * HD);
    const uint4* gM3 = (const uint4*)(hM3   + (size_t)rg * HD);
    uint4* lM2 = (uint4*)(sM2 + wv * HD);
    uint4* lW2 = (uint4*)(sW2 + wv * HD);
    uint4* lH2 = (uint4*)(sH2 + wv * HD);
    uint4* lM3 = (uint4*)(sM3 + wv * HD);
    #pragma unroll
    for (int i = 0; i < 2; ++i) {
      lM2[lane + 64 * i] = gM2[lane + 64 * i];
      lW2[lane + 64 * i] = gW2[lane + 64 * i];
      lH2[lane + 64 * i] = gH2[lane + 64 * i];
      lM3[lane + 64 * i] = gM3[lane + 64 * i];
    }
  }
  // fold biases (3 sequential rounds through s_ftmp)
  if (tid < 512) *(float2*)(s_ftmp + tid * 2) = *(const float2*)(Wb0 + tid * 2);
  __syncthreads();
  b1 = bih1[rg] + bhh1[rg] + wredsum(dotp(Wih1 + (size_t)rg * 2 * HD, s_ftmp, HD, lane));
  __syncthreads();
  if (tid < 512) *(float2*)(s_ftmp + tid * 2) = *(const float2*)(Wb1 + tid * 2);
  __syncthreads();
  b2 = bih2[rg] + bhh2[rg] + wredsum(dotp(Wih2 + (size_t)rg * 2 * HD, s_ftmp, HD, lane));
  __syncthreads();
  if (tid < 512) *(float2*)(s_ftmp + tid * 2) = *(const float2*)(Wb2 + tid * 2);
  __syncthreads();
  b3 = bih3[rg] + bhh3[rg] + wredsum(dotp(Wih3 + (size_t)rg * HD, s_ftmp, HD, lane));
  if (gi == 0) vbR3 = Vb3[jown];
  if (gi == 2) vbR2 = Vb2[jown];
  if (wv == 1) vbZ  = Vb1[bid];
  if (tid < 4) { s_c2own[tid] = 0.f; s_c3own[tid] = 0.f; }
  if (tid == 0) {                       // publish zero h2/TD2 (buf 1), h3
    uint2 z2 = make_uint2(0u, 0u);
    cstoreU2(d_h2h[1] + bid * 4, z2);
    cstoreU2(d_TD2h[1] + bid * 4, z2);
    cstoreU2(d_h3h + bid * 4, z2);
  }
  if (tid < 64) {                       // softmax(r1) -> TD0(0); loss0(0)
    float4 z4 = *(const float4*)(r1 + tid * 4);
    float m = wredmax(fmaxf(fmaxf(z4.x, z4.y), fmaxf(z4.z, z4.w)));
    float e0 = __expf(z4.x - m), e1 = __expf(z4.y - m);
    float e2 = __expf(z4.z - m), e3 = __expf(z4.w - m);
    float inv = 1.f / wredsum((e0 + e1) + (e2 + e3));
    float p0 = e0 * inv, p1 = e1 * inv, p2 = e2 * inv, p3 = e3 * inv;
    float4 xv = *(const float4*)(x + tid * 4);
    *(uint2*)(s_small + tid * 4) =
        make_uint2(packh2(xv.x - p0, xv.y - p1), packh2(xv.z - p2, xv.w - p3));
    if (iswg0) {
      float u = xv.x * __logf(p0) + (1.f - xv.x) * __logf(1.f - p0)
              + xv.y * __logf(p1) + (1.f - xv.y) * __logf(1.f - p1)
              + xv.z * __logf(p2) + (1.f - xv.z) * __logf(1.f - p2)
              + xv.w * __logf(p3) + (1.f - xv.w) * __logf(1.f - p3);
      u = wredsum(u);
      if (tid == 0) { loss_acc -= u; fll_acc -= u; }
    }
  }
  __syncthreads();
  {                                     // g1(0) rows (TD1=h1=0 at t=0)
    float s = wredsum(dotH256(hM1 + (size_t)rg * CD, s_small, lane)) + b1;
    if (lane == 0) s_gateA[wv] = s;
  }
  __syncthreads();
  if (tid < 64) {                       // cell1(0), rec2init = r2
    float h = 0.f, td = 0.f;
    if (lane < 4) {
      float gI = s_gateA[lane * 4 + 0], gF = s_gateA[lane * 4 + 1];
      float gG = s_gateA[lane * 4 + 2], gO = s_gateA[lane * 4 + 3];
      (void)gF;
      float cn = sigf(gI) * tanhfast(gG);   // c1 = 0
      h  = sigf(gO) * tanhfast(cn);
      td = h - r2[bid * 4 + lane];
      s_c1own[lane] = cn;
    }
    uint2 uh, ut;
    uh.x = packh2(__shfl(h, 0), __shfl(h, 1));  uh.y = packh2(__shfl(h, 2), __shfl(h, 3));
    ut.x = packh2(__shfl(td, 0), __shfl(td, 1)); ut.y = packh2(__shfl(td, 2), __shfl(td, 3));
    if (lane == 0) { cstoreU2(d_h1h + bid * 4, uh); cstoreU2(d_TD1h + bid * 4, ut); }
  }
  gbar(ep);

  for (int t = 0; t < TT; ++t) {
    const int pb = t & 1, pbm = pb ^ 1;   // h2/TD2 parity buffers

    // ========== P(t): read vectors; g2(t), z1(t), rec3(t-1); cell2(t) =====
    {
      const int grp = tid >> 8, k = tid & 255;
      if (grp == 0) {
        *(uint2*)(s_TD1 + k * 4) = cloadU2(d_TD1h + k * 4);
        *(uint2*)(s_h1 + k * 4)  = cloadU2(d_h1h + k * 4);
      } else if (grp == 1) {
        *(uint2*)(s_TD2 + k * 4) = cloadU2(d_TD2h[pbm] + k * 4);
      } else if (grp == 2) {
        *(uint2*)(s_h2 + k * 4)  = cloadU2(d_h2h[pbm] + k * 4);
      } else {
        *(uint2*)(s_h3 + k * 4)  = cloadU2(d_h3h + k * 4);
      }
      __syncthreads();
      if (w0) {                          // LAM * sum|TD1(t)|
        float a = 0.f;
        #pragma unroll
        for (int kk = 0; kk < 16; ++kk) a += fabsf(h2f(s_TD1[tid + 64 * kk]));
        a = wredsum(a);
        if (tid == 0) loss_acc += LAMF * a;
      }
      {                                  // g2 row (LDS weights)
        float s = dotH(sM2 + wv * HD, s_TD1, lane)
                + dotH(sW2 + wv * HD, s_TD2, lane)
                + dotH(sH2 + wv * HD, s_h2,  lane);
        s = wredsum(s);
        if (lane == 0) s_gateA[wv] = s + b2;
      }
      if (gi == 0) {                     // rec3(t-1) row for own element
        if (t > 0) {
          float s = wredsum(dotH(hVw3 + (size_t)jown * HD, s_h3, lane)) + vbR3;
          if (lane == 0) s_rec[slot] = s;
        } else if (lane == 0) s_rec[slot] = r3[jown];
      }
      if (wv == 1) {                     // z1 row bid
        float s = wredsum(dotH(hVw1 + (size_t)bid * HD, s_h1, lane)) + vbZ;
        if (lane == 0) cstore(&d_z1[bid], s);
      }
      __syncthreads();
      if (tid < 64) {                    // cell2(t) -> publish h2,TD2 (buf pb)
        float h = 0.f, td = 0.f;
        if (lane < 4) {
          float gI = s_gateA[lane * 4 + 0], gF = s_gateA[lane * 4 + 1];
          float gG = s_gateA[lane * 4 + 2], gO = s_gateA[lane * 4 + 3];
          float cn = sigf(gF) * s_c2own[lane] + sigf(gI) * tanhfast(gG);
          h  = sigf(gO) * tanhfast(cn);
          td = h - s_rec[lane];
          s_c2own[lane] = cn;
        }
        uint2 uh, ut;
        uh.x = packh2(__shfl(h, 0), __shfl(h, 1));  uh.y = packh2(__shfl(h, 2), __shfl(h, 3));
        ut.x = packh2(__shfl(td, 0), __shfl(td, 1)); ut.y = packh2(__shfl(td, 2), __shfl(td, 3));
        if (lane == 0) { cstoreU2(d_h2h[pb] + bid * 4, uh); cstoreU2(d_TD2h[pb] + bid * 4, ut); }
      }
    }
    gbar(ep);

    // ========== Q(t): softmax; g3(t), g1(t+1), rec2(t); cell3, cell1 ======
    {
      const int grp = tid >> 8, k = tid & 255;
      if (grp == 0)      *(uint2*)(s_TD2 + k * 4) = cloadU2(d_TD2h[pb] + k * 4);
      else if (grp == 1) *(uint2*)(s_h2 + k * 4)  = cloadU2(d_h2h[pb] + k * 4);
      if (tid < 64) {                    // softmax(z1(t))
        float2 za = cload2(&d_z1[tid * 4]), zb = cload2(&d_z1[tid * 4 + 2]);
        float m = wredmax(fmaxf(fmaxf(za.x, za.y), fmaxf(zb.x, zb.y)));
        float e0 = __expf(za.x - m), e1 = __expf(za.y - m);
        float e2 = __expf(zb.x - m), e3 = __expf(zb.y - m);
        float inv = 1.f / wredsum((e0 + e1) + (e2 + e3));
        float p0 = e0 * inv, p1 = e1 * inv, p2 = e2 * inv, p3 = e3 * inv;
        if (t < TT - 1) {
          float4 xv = *(const float4*)(x + (size_t)(t + 1) * CD + tid * 4);
          *(uint2*)(s_small + tid * 4) =
              make_uint2(packh2(xv.x - p0, xv.y - p1), packh2(xv.z - p2, xv.w - p3));
          if (iswg0) {
            float u = xv.x * __logf(p0) + (1.f - xv.x) * __logf(1.f - p0)
                    + xv.y * __logf(p1) + (1.f - xv.y) * __logf(1.f - p1)
                    + xv.z * __logf(p2) + (1.f - xv.z) * __logf(1.f - p2)
                    + xv.w * __logf(p3) + (1.f - xv.w) * __logf(1.f - p3);
            u = wredsum(u);
            if (tid == 0) { loss_acc -= u; fll_acc -= u; }
          }
        }
        if (iswg0) {
          float* po = out + 2 + (size_t)t * CD + tid * 4;
          po[0] = p0; po[1] = p1; po[2] = p2; po[3] = p3;
        }
      }
      __syncthreads();
      if (w0) {                          // LAM^2 * sum|TD2(t)|
        float a = 0.f;
        #pragma unroll
        for (int kk = 0; kk < 16; ++kk) a += fabsf(h2f(s_TD2[tid + 64 * kk]));
        a = wredsum(a);
        if (tid == 0) loss_acc += (LAMF * LAMF) * a;
      }
      if (t < TT - 1) {
        {                                // g3 row (M3 LDS, Whh3 L2; h3 = h3(t-1))
          float s = dotH(sM3 + wv * HD, s_TD2, lane)
                  + dotH(hWhh3 + (size_t)rg * HD, s_h3, lane);
          s = wredsum(s);
          if (lane == 0) s_gateB[wv] = s + b3;
        }
        {                                // g1(t+1) row
          float s = dotH256(hM1 + (size_t)rg * CD, s_small, lane)
                  + dotH(hW1b  + (size_t)rg * HD, s_TD1, lane)
                  + dotH(hWhh1 + (size_t)rg * HD, s_h1,  lane);
          s = wredsum(s);
          if (lane == 0) s_gateA[wv] = s + b1;
        }
        if (gi == 2) {                   // rec2(t) row for own element
          float s = wredsum(dotH(hVw2 + (size_t)jown * HD, s_h2, lane)) + vbR2;
          if (lane == 0) s_rec[slot] = s;
        }
        __syncthreads();
        if (tid < 64) {                  // cell3(t) + cell1(t+1) -> publish
          float h3n = 0.f, h1n = 0.f, td1 = 0.f;
          if (lane < 4) {
            {
              float gI = s_gateB[lane * 4 + 0], gF = s_gateB[lane * 4 + 1];
              float gG = s_gateB[lane * 4 + 2], gO = s_gateB[lane * 4 + 3];
              float cn = sigf(gF) * s_c3own[lane] + sigf(gI) * tanhfast(gG);
              h3n = sigf(gO) * tanhfast(cn);
              s_c3own[lane] = cn;
            }
            {
              float gI = s_gateA[lane * 4 + 0], gF = s_gateA[lane * 4 + 1];
              float gG = s_gateA[lane * 4 + 2], gO = s_gateA[lane * 4 + 3];
              float cn = sigf(gF) * s_c1own[lane] + sigf(gI) * tanhfast(gG);
              h1n = sigf(gO) * tanhfast(cn);
              td1 = h1n - s_rec[lane];
              s_c1own[lane] = cn;
            }
          }
          uint2 u3, u1, utd;
          u3.x = packh2(__shfl(h3n, 0), __shfl(h3n, 1)); u3.y = packh2(__shfl(h3n, 2), __shfl(h3n, 3));
          u1.x = packh2(__shfl(h1n, 0), __shfl(h1n, 1)); u1.y = packh2(__shfl(h1n, 2), __shfl(h1n, 3));
          utd.x = packh2(__shfl(td1, 0), __shfl(td1, 1)); utd.y = packh2(__shfl(td1, 2), __shfl(td1, 3));
          if (lane == 0) {
            cstoreU2(d_h3h + bid * 4, u3);
            cstoreU2(d_h1h + bid * 4, u1);
            cstoreU2(d_TD1h + bid * 4, utd);
          }
        }
        gbar(ep);
      }
    }
  }

  if (iswg0 && tid == 0) { out[0] = loss_acc; out[1] = fll_acc; }
}

extern "C" void kernel_launch(void* const* d_in, const int* in_sizes, int n_in,
                              void* d_out, int out_size, void* d_ws, size_t ws_size,
                              hipStream_t stream) {
  const float* x    = (const float*)d_in[0];
  const float* Wih1 = (const float*)d_in[1];
  const float* Whh1 = (const float*)d_in[2];
  const float* bih1 = (const float*)d_in[3];
  const float* bhh1 = (const float*)d_in[4];
  const float* Vw1  = (const float*)d_in[5];
  const float* Vb1  = (const float*)d_in[6];
  const float* Wih2 = (const float*)d_in[7];
  const float* Whh2 = (const float*)d_in[8];
  const float* bih2 = (const float*)d_in[9];
  const float* bhh2 = (const float*)d_in[10];
  const float* Vw2  = (const float*)d_in[11];
  const float* Vb2  = (const float*)d_in[12];
  const float* Wih3 = (const float*)d_in[13];
  const float* Whh3 = (const float*)d_in[14];
  const float* bih3 = (const float*)d_in[15];
  const float* bhh3 = (const float*)d_in[16];
  const float* Vw3  = (const float*)d_in[17];
  const float* Vb3  = (const float*)d_in[18];
  const float* Ww0  = (const float*)d_in[19];
  const float* Wb0  = (const float*)d_in[20];
  const float* Ww1  = (const float*)d_in[21];
  const float* Wb1  = (const float*)d_in[22];
  const float* Ww2  = (const float*)d_in[23];
  const float* Wb2  = (const float*)d_in[24];
  const float* r1   = (const float*)d_in[25];
  const float* r2   = (const float*)d_in[26];
  const float* r3   = (const float*)d_in[27];

  static int smem_set = 0;
  if (!smem_set) {
    hipFuncSetAttribute((const void*)pc_main,
                        hipFuncAttributeMaxDynamicSharedMemorySize, SMEMB);
    smem_set = 1;
  }

  pc_conv<<<1024, 256, 0, stream>>>(Wih1, Whh1, Wih2, Whh2, Whh3, Vw1, Vw2, Vw3);
  pc_fold<<<2304, 256, 0, stream>>>(Wih1, Wih2, Wih3, Ww0, Ww1, Ww2);
  pc_init<<<1, NWG, 0, stream>>>();
  pc_main<<<NWG, NTH, SMEMB, stream>>>(x, Wih1, Whh1, bih1, bhh1, Vw1, Vb1,
                                       Wih2, Whh2, bih2, bhh2, Vw2, Vb2,
                                       Wih3, Whh3, bih3, bhh3, Vw3, Vb3,
                                       Ww0, Wb0, Ww1, Wb1, Ww2, Wb2,
                                       r1, r2, r3, (float*)d_out);
}